// Round 3
// baseline (9178.561 us; speedup 1.0000x reference)
//
#include <hip/hip_runtime.h>
#include <cstdint>
#include <cstddef>

#define SEQ   512
#define BATCH 64
#define INDIM 512
#define HID   1024

typedef short bf16x8 __attribute__((ext_vector_type(8)));
typedef float f32x4  __attribute__((ext_vector_type(4)));
typedef unsigned long long ull;

#define MFMA16(A,B,C) __builtin_amdgcn_mfma_f32_16x16x32_bf16(A,B,C,0,0,0)

// ---- workspace layout (bytes) ----
// cnt   : 4 group counters, 128-B stride, in [0,512)
// h_hi  : [4 grp][2 buf][32 kc][64 lane][8] u16 = 262144 B   (h exchange, ping-pong)
// h_lo  : same                                   262144 B
// rh_hi : [4 grp][32 kc][64 lane][8] u16       = 131072 B   (r*h exchange, single buf)
// rh_lo : same                                   131072 B
// W_hi  : [64 jb][48 kc][3 gate][64 lane][8]   = 9437184 B
// W_lo  : same                                   9437184 B
#define WS_HHI 512
#define WS_HLO (WS_HHI + 262144)
#define WS_RHI (WS_HLO + 262144)
#define WS_RLO (WS_RHI + 131072)
#define WS_WHI (WS_RLO + 131072)
#define WS_WLO (WS_WHI + 9437184)
#define WS_END (WS_WLO + 9437184)   // 19,661,312 B (< round-2's 19.4 MB, known to fit)

__device__ __forceinline__ unsigned short f2bf(float f) {
  unsigned u = __float_as_uint(f);
  unsigned r = (u + 0x7fffu + ((u >> 16) & 1u)) >> 16;  // RNE
  return (unsigned short)r;
}
__device__ __forceinline__ float bf2f(unsigned short h) {
  return __uint_as_float(((unsigned)h) << 16);
}
__device__ __forceinline__ void splitf(float x, unsigned short& hi, unsigned short& lo) {
  unsigned short h = f2bf(x);
  float r = x - bf2f(h);          // exact
  hi = h; lo = f2bf(r);           // combined rel err ~2^-18
}

// ---------------- prep: pack weights (B-fragment order, hi+lo) — unchanged ----------------
// idx = ((jb*48+kc)*3+g)*64+lane ; lane holds W[kc*32+(lane>>4)*8 + 0..7][jb*16+(lane&15)]
__global__ void prep_w(const float* __restrict__ Wz, const float* __restrict__ Wr,
                       const float* __restrict__ Wm,
                       bf16x8* __restrict__ wh, bf16x8* __restrict__ wl) {
  int n    = blockIdx.x * 256 + threadIdx.x;     // 589,824 threads
  int lane = n & 63;
  int m    = n >> 6;
  int g    = m % 3;
  int m2   = m / 3;
  int kc   = m2 % 48;
  int jb   = m2 / 48;
  const float* W = (g == 0) ? Wz : (g == 1) ? Wr : Wm;
  int k0 = kc*32 + ((lane >> 4) << 3);
  int nn = jb*16 + (lane & 15);
  bf16x8 vh, vl;
  #pragma unroll
  for (int j = 0; j < 8; ++j) {
    unsigned short a, b;
    splitf(W[(size_t)(k0 + j)*HID + nn], a, b);
    vh[j] = (short)a; vl[j] = (short)b;
  }
  wh[n] = vh; wl[n] = vl;
}

// ---------------- prep: pack init_h into each group's buffer 0 (hi+lo) ----------------
__global__ void prep_h(const float* __restrict__ h0,
                       bf16x8* __restrict__ hh, bf16x8* __restrict__ hl) {
  int n = blockIdx.x * 256 + threadIdx.x;        // 8192 threads
  int b = n >> 7;                                 // global batch row
  int j = (n & 127) << 3;
  const float* s = h0 + (size_t)b*HID + j;
  float4 f0 = ((const float4*)s)[0];
  float4 f1 = ((const float4*)s)[1];
  float v[8] = {f0.x,f0.y,f0.z,f0.w,f1.x,f1.y,f1.z,f1.w};
  bf16x8 vh, vl;
  #pragma unroll
  for (int q = 0; q < 8; ++q) {
    unsigned short a, c;
    splitf(v[q], a, c);
    vh[q] = (short)a; vl[q] = (short)c;
  }
  int g    = b >> 4;
  int kc2  = j >> 5;
  int lane = (b & 15) + (((j >> 3) & 3) << 4);
  size_t idx = (size_t)g*4096 + (size_t)kc2*64 + lane;   // buf 0 of group g
  hh[idx] = vh; hl[idx] = vl;
}

// load 8 A-fragments (agent-scope, cache-bypassing); stride between kc = 64 frags = 128 ull
__device__ __forceinline__ void loadfrags(bf16x8* dst, const ull* base) {
  #pragma unroll
  for (int i = 0; i < 8; ++i) {
    ull u0 = __hip_atomic_load((ull*)(base + (size_t)i*128),
                               __ATOMIC_RELAXED, __HIP_MEMORY_SCOPE_AGENT);
    ull u1 = __hip_atomic_load((ull*)(base + (size_t)i*128 + 1),
                               __ATOMIC_RELAXED, __HIP_MEMORY_SCOPE_AGENT);
    union { ull u[2]; bf16x8 v; } t;
    t.u[0] = u0; t.u[1] = u1;
    dst[i] = t.v;
  }
}

// ---------------- main persistent GRU kernel ----------------
// 256 blocks x 256 threads. blockIdx = g*64 + jb.
// Block (g,jb): batch rows [g*16,g*16+16), HID cols [jb*16,jb*16+16), full K.
// 4 waves K-split (8 kc each of the h-part); partials reduced via LDS.
__global__ __launch_bounds__(256, 1)
void gru_main(const float* __restrict__ emb,
              const float* __restrict__ bz, const float* __restrict__ br,
              const float* __restrict__ bm, const float* __restrict__ init_h,
              float* __restrict__ out,
              const bf16x8* __restrict__ wh_all, const bf16x8* __restrict__ wl_all,
              unsigned short* __restrict__ hp_hi, unsigned short* __restrict__ hp_lo,
              unsigned short* __restrict__ rp_hi, unsigned short* __restrict__ rp_lo,
              unsigned int* __restrict__ cnt_base)
{
  const int tid  = threadIdx.x;
  const int w    = tid >> 6;
  const int lane = tid & 63;
  const int jb   = blockIdx.x & 63;
  const int g    = blockIdx.x >> 6;
  const int jc   = jb*16 + (lane & 15);   // C/D col
  const int rb   = (lane >> 4) << 2;      // C/D row base within 16-row tile
  const int bb   = g*16 + rb;             // global batch row base
  unsigned int* cnt = cnt_base + g*32;    // group-local counter (128-B stride)

  const float bzj = bz[jc], brj = br[jc], bmj = bm[jc];
  float st[4];
  #pragma unroll
  for (int r = 0; r < 4; ++r) st[r] = init_h[(size_t)(bb + r)*HID + jc];

  __shared__ f32x4 red1[2][4][64];
  __shared__ f32x4 red2[2][4][64];

  // ---- preload this wave's h-part W slice into registers (48 frags = 192 VGPR) ----
  const bf16x8* whB = wh_all + ((size_t)jb*48*3)*64 + lane;
  const bf16x8* wlB = wl_all + ((size_t)jb*48*3)*64 + lane;
  bf16x8 Wh[8][3], Wl[8][3];
  #pragma unroll
  for (int i = 0; i < 8; ++i) {
    int kc = 16 + w*8 + i;
    #pragma unroll
    for (int gt = 0; gt < 3; ++gt) {
      Wh[i][gt] = whB[(size_t)(kc*3 + gt)*64];
      Wl[i][gt] = wlB[(size_t)(kc*3 + gt)*64];
    }
  }

  // publish-index constants (owner side)
  const int kc2w   = jc >> 5;
  const int l2base = ((jc & 31) >> 3) << 4;
  const int e7     = jc & 7;

  // A-load base pointers (frag granularity, 2 ull per frag)
  const ull* hbase_hi = (const ull*)hp_hi + ((size_t)g*4096 + (size_t)(w*8)*64 + lane)*2;
  const ull* hbase_lo = (const ull*)hp_lo + ((size_t)g*4096 + (size_t)(w*8)*64 + lane)*2;
  const ull* rbase_hi = (const ull*)rp_hi + ((size_t)g*2048 + (size_t)(w*8)*64 + lane)*2;
  const ull* rbase_lo = (const ull*)rp_lo + ((size_t)g*2048 + (size_t)(w*8)*64 + lane)*2;

  // e-part A source: lane holds emb[t][g*16+(lane&15)][kce*32+(lane>>4)*8 .. +7]
  const float* ebase = emb + (size_t)(g*16 + (lane & 15))*INDIM + ((lane >> 4) << 3);

  for (int t = 0; t < SEQ; ++t) {
    f32x4 az  = {0.f,0.f,0.f,0.f};
    f32x4 ar  = {0.f,0.f,0.f,0.f};
    f32x4 amx = {0.f,0.f,0.f,0.f};
    f32x4 amh = {0.f,0.f,0.f,0.f};

    // ---- e-part (x-projections, K-slice kce = w*4..w*4+3): pre-barrier, hides spin ----
    const float* et = ebase + (size_t)t*(BATCH*INDIM);
    #pragma unroll
    for (int q = 0; q < 4; ++q) {
      int kce = w*4 + q;
      const float* s = et + kce*32;
      float4 f0 = ((const float4*)s)[0];
      float4 f1 = ((const float4*)s)[1];
      float v[8] = {f0.x,f0.y,f0.z,f0.w,f1.x,f1.y,f1.z,f1.w};
      bf16x8 eh, el;
      #pragma unroll
      for (int qq = 0; qq < 8; ++qq) {
        unsigned short a, b;
        splitf(v[qq], a, b);
        eh[qq] = (short)a; el[qq] = (short)b;
      }
      bf16x8 wzh = whB[(size_t)(kce*3+0)*64], wzl = wlB[(size_t)(kce*3+0)*64];
      bf16x8 wrh = whB[(size_t)(kce*3+1)*64], wrl = wlB[(size_t)(kce*3+1)*64];
      bf16x8 wmh = whB[(size_t)(kce*3+2)*64], wml = wlB[(size_t)(kce*3+2)*64];
      az  = MFMA16(eh, wzh, az);  az  = MFMA16(eh, wzl, az);  az  = MFMA16(el, wzh, az);
      ar  = MFMA16(eh, wrh, ar);  ar  = MFMA16(eh, wrl, ar);  ar  = MFMA16(el, wrh, ar);
      amx = MFMA16(eh, wmh, amx); amx = MFMA16(eh, wml, amx); amx = MFMA16(el, wmh, amx);
    }

    // ---- barrier A: h(t) published by all blocks of this group ----
    if (t > 0) {
      if (tid == 0) {
        const unsigned tgt = 64u*(unsigned)(2*t);
        while (__hip_atomic_load(cnt, __ATOMIC_RELAXED, __HIP_MEMORY_SCOPE_AGENT) < tgt)
          __builtin_amdgcn_s_sleep(1);
      }
      __syncthreads();
    }

    // ---- phase 1: z,r h-matmul over this wave's K-slice ----
    const int buf = t & 1;
    const ull* hbh = hbase_hi + (size_t)buf*4096;   // 2048 frags * 2 ull
    const ull* hbl = hbase_lo + (size_t)buf*4096;
    bf16x8 Ah[8], Al[8];
    loadfrags(Ah, hbh);
    loadfrags(Al, hbl);
    #pragma unroll
    for (int i = 0; i < 8; ++i) {
      az = MFMA16(Ah[i], Wh[i][0], az);
      az = MFMA16(Ah[i], Wl[i][0], az);
      az = MFMA16(Al[i], Wh[i][0], az);
      ar = MFMA16(Ah[i], Wh[i][1], ar);
      ar = MFMA16(Ah[i], Wl[i][1], ar);
      ar = MFMA16(Al[i], Wh[i][1], ar);
    }

    // ---- reduce az, ar across the 4 waves ----
    red1[0][w][lane] = az;
    red1[1][w][lane] = ar;
    __syncthreads();
    f32x4 azF = red1[0][0][lane] + red1[0][1][lane] + red1[0][2][lane] + red1[0][3][lane];
    f32x4 arF = red1[1][0][lane] + red1[1][1][lane] + red1[1][2][lane] + red1[1][3][lane];

    // ---- pointwise 1: z, r, rh = r*h ; publish rh ----
    float z[4];
    #pragma unroll
    for (int r = 0; r < 4; ++r) {
      z[r]     = 1.f / (1.f + __expf(-(azF[r] + bzj)));
      float rr = 1.f / (1.f + __expf(-(arF[r] + brj)));
      float rhv = rr * st[r];
      if (w == 0) {
        unsigned short sh, sl;
        splitf(rhv, sh, sl);
        int lane2 = (rb + r) + l2base;
        size_t eidx = ((size_t)kc2w*64 + lane2)*8 + e7;
        __hip_atomic_store(rp_hi + (size_t)g*16384 + eidx, sh,
                           __ATOMIC_RELAXED, __HIP_MEMORY_SCOPE_AGENT);
        __hip_atomic_store(rp_lo + (size_t)g*16384 + eidx, sl,
                           __ATOMIC_RELAXED, __HIP_MEMORY_SCOPE_AGENT);
      }
    }
    if (tid == 0)
      __hip_atomic_fetch_add(cnt, 1u, __ATOMIC_RELEASE, __HIP_MEMORY_SCOPE_AGENT);

    // ---- barrier B: rh published by all blocks of this group ----
    if (tid == 0) {
      const unsigned tgt = 64u*(unsigned)(2*t + 1);
      while (__hip_atomic_load(cnt, __ATOMIC_RELAXED, __HIP_MEMORY_SCOPE_AGENT) < tgt)
        __builtin_amdgcn_s_sleep(1);
    }
    __syncthreads();

    // ---- phase 2: m h-matmul over rh ----
    bf16x8 Bh[8], Bl[8];
    loadfrags(Bh, rbase_hi);
    loadfrags(Bl, rbase_lo);
    #pragma unroll
    for (int i = 0; i < 8; ++i) {
      amh = MFMA16(Bh[i], Wh[i][2], amh);
      amh = MFMA16(Bh[i], Wl[i][2], amh);
      amh = MFMA16(Bl[i], Wh[i][2], amh);
    }

    // ---- reduce amx, amh ----
    red2[0][w][lane] = amx;
    red2[1][w][lane] = amh;
    __syncthreads();
    f32x4 amxF = red2[0][0][lane] + red2[0][1][lane] + red2[0][2][lane] + red2[0][3][lane];
    f32x4 amhF = red2[1][0][lane] + red2[1][1][lane] + red2[1][2][lane] + red2[1][3][lane];

    // ---- pointwise 2: h_tilde, h_new ; publish h(t+1) ----
    const int obuf = buf ^ 1;
    float hnv[4];
    #pragma unroll
    for (int r = 0; r < 4; ++r) {
      float pm = amxF[r] + bmj + amhF[r];
      float e2 = __expf(2.f*pm);
      float ht = 1.f - 2.f/(e2 + 1.f);
      float hn = st[r] + z[r]*(ht - st[r]);
      st[r] = hn; hnv[r] = hn;
      if (w == 0) {
        unsigned short sh, sl;
        splitf(hn, sh, sl);
        int lane2 = (rb + r) + l2base;
        size_t eidx = ((size_t)kc2w*64 + lane2)*8 + e7;
        size_t base = (size_t)g*32768 + (size_t)obuf*16384;
        __hip_atomic_store(hp_hi + base + eidx, sh,
                           __ATOMIC_RELAXED, __HIP_MEMORY_SCOPE_AGENT);
        __hip_atomic_store(hp_lo + base + eidx, sl,
                           __ATOMIC_RELAXED, __HIP_MEMORY_SCOPE_AGENT);
      }
    }
    if (tid == 0)
      __hip_atomic_fetch_add(cnt, 1u, __ATOMIC_RELEASE, __HIP_MEMORY_SCOPE_AGENT);

    // ---- output (after arrival; doesn't block the protocol) ----
    if (w == 0) {
      #pragma unroll
      for (int r = 0; r < 4; ++r)
        __builtin_nontemporal_store(hnv[r],
            out + (size_t)(bb + r)*(SEQ*HID) + (size_t)t*HID + jc);
    }
  }
}

extern "C" void kernel_launch(void* const* d_in, const int* in_sizes, int n_in,
                              void* d_out, int out_size, void* d_ws, size_t ws_size,
                              hipStream_t stream) {
  const float* emb = (const float*)d_in[0];
  const float* h0  = (const float*)d_in[1];
  const float* Wz  = (const float*)d_in[2];
  const float* bz  = (const float*)d_in[3];
  const float* Wr  = (const float*)d_in[4];
  const float* br  = (const float*)d_in[5];
  const float* Wm  = (const float*)d_in[6];
  const float* bm  = (const float*)d_in[7];
  float* out = (float*)d_out;

  if (ws_size < (size_t)WS_END) return;

  char* ws = (char*)d_ws;
  unsigned int*   cnt  = (unsigned int*)ws;
  unsigned short* hphi = (unsigned short*)(ws + WS_HHI);
  unsigned short* hplo = (unsigned short*)(ws + WS_HLO);
  unsigned short* rphi = (unsigned short*)(ws + WS_RHI);
  unsigned short* rplo = (unsigned short*)(ws + WS_RLO);
  bf16x8*         wph  = (bf16x8*)(ws + WS_WHI);
  bf16x8*         wpl  = (bf16x8*)(ws + WS_WLO);

  hipMemsetAsync(ws, 0, 512, stream);                       // zero group counters
  prep_w<<<2304, 256, 0, stream>>>(Wz, Wr, Wm, wph, wpl);
  prep_h<<<32,   256, 0, stream>>>(h0, (bf16x8*)hphi, (bf16x8*)hplo);
  gru_main<<<256, 256, 0, stream>>>(emb, bz, br, bm, h0, out,
                                    wph, wpl, hphi, hplo, rphi, rplo, cnt);
}

// Round 4
// 8518.071 us; speedup vs baseline: 1.0775x; 1.0775x over previous
//
#include <hip/hip_runtime.h>
#include <cstdint>
#include <cstddef>

#define SEQ   512
#define BATCH 64
#define INDIM 512
#define HID   1024

typedef short bf16x8 __attribute__((ext_vector_type(8)));
typedef float f32x4  __attribute__((ext_vector_type(4)));
typedef unsigned long long ull;

#define MFMA16(A,B,C) __builtin_amdgcn_mfma_f32_16x16x32_bf16(A,B,C,0,0,0)

// ---- workspace layout (bytes) ----
// fh    : [4 grp][64 jb][16] u32 (one 64-B line per producer)  16384 B
// fr    : same                                                  16384 B
// h_hi  : [4][2 buf][32 kc][64 lane][8] u16                    262144 B
// h_lo  : same                                                  262144 B
// rh_hi : [4][32 kc][64 lane][8] u16                           131072 B
// rh_lo : same                                                  131072 B
// W_hi  : [64 jb][48 kc][3 gate][64 lane][8] bf16             9437184 B
// W_lo  : same                                                 9437184 B
#define WS_FH  0
#define WS_FR  16384
#define WS_HHI 32768
#define WS_HLO (WS_HHI + 262144)
#define WS_RHI (WS_HLO + 262144)
#define WS_RLO (WS_RHI + 131072)
#define WS_WHI (WS_RLO + 131072)
#define WS_WLO (WS_WHI + 9437184)
#define WS_END (WS_WLO + 9437184)   // 19,693,568 B (ws proven >= 43 MB in round 1)

__device__ __forceinline__ unsigned short f2bf(float f) {
  unsigned u = __float_as_uint(f);
  unsigned r = (u + 0x7fffu + ((u >> 16) & 1u)) >> 16;  // RNE
  return (unsigned short)r;
}
__device__ __forceinline__ float bf2f(unsigned short h) {
  return __uint_as_float(((unsigned)h) << 16);
}
__device__ __forceinline__ void splitf(float x, unsigned short& hi, unsigned short& lo) {
  unsigned short h = f2bf(x);
  float r = x - bf2f(h);          // exact
  hi = h; lo = f2bf(r);           // combined rel err ~2^-18
}

// ---------------- prep: pack weights (B-fragment order, hi+lo) ----------------
__global__ void prep_w(const float* __restrict__ Wz, const float* __restrict__ Wr,
                       const float* __restrict__ Wm,
                       bf16x8* __restrict__ wh, bf16x8* __restrict__ wl) {
  int n    = blockIdx.x * 256 + threadIdx.x;     // 589,824 threads
  int lane = n & 63;
  int m    = n >> 6;
  int g    = m % 3;
  int m2   = m / 3;
  int kc   = m2 % 48;
  int jb   = m2 / 48;
  const float* W = (g == 0) ? Wz : (g == 1) ? Wr : Wm;
  int k0 = kc*32 + ((lane >> 4) << 3);
  int nn = jb*16 + (lane & 15);
  bf16x8 vh, vl;
  #pragma unroll
  for (int j = 0; j < 8; ++j) {
    unsigned short a, b;
    splitf(W[(size_t)(k0 + j)*HID + nn], a, b);
    vh[j] = (short)a; vl[j] = (short)b;
  }
  wh[n] = vh; wl[n] = vl;
}

// ---------------- prep: pack init_h into each group's buffer 0 (hi+lo) ----------------
__global__ void prep_h(const float* __restrict__ h0,
                       bf16x8* __restrict__ hh, bf16x8* __restrict__ hl) {
  int n = blockIdx.x * 256 + threadIdx.x;        // 8192 threads
  int b = n >> 7;
  int j = (n & 127) << 3;
  const float* s = h0 + (size_t)b*HID + j;
  float4 f0 = ((const float4*)s)[0];
  float4 f1 = ((const float4*)s)[1];
  float v[8] = {f0.x,f0.y,f0.z,f0.w,f1.x,f1.y,f1.z,f1.w};
  bf16x8 vh, vl;
  #pragma unroll
  for (int q = 0; q < 8; ++q) {
    unsigned short a, c;
    splitf(v[q], a, c);
    vh[q] = (short)a; vl[q] = (short)c;
  }
  int g    = b >> 4;
  int kc2  = j >> 5;
  int lane = (b & 15) + (((j >> 3) & 3) << 4);
  size_t idx = (size_t)g*4096 + (size_t)kc2*64 + lane;   // buf 0 of group g
  hh[idx] = vh; hl[idx] = vl;
}

// load 8 A-fragments (agent-scope, LLC-coherent); kc stride = 64 frags = 128 ull
__device__ __forceinline__ void loadfrags(bf16x8* dst, const ull* base) {
  #pragma unroll
  for (int i = 0; i < 8; ++i) {
    ull u0 = __hip_atomic_load((ull*)(base + (size_t)i*128),
                               __ATOMIC_RELAXED, __HIP_MEMORY_SCOPE_AGENT);
    ull u1 = __hip_atomic_load((ull*)(base + (size_t)i*128 + 1),
                               __ATOMIC_RELAXED, __HIP_MEMORY_SCOPE_AGENT);
    union { ull u[2]; bf16x8 v; } t;
    t.u[0] = u0; t.u[1] = u1;
    dst[i] = t.v;
  }
}

// per-wave wait: 64 lanes poll 16 distinct flag lines (4 lanes/flag), exit on ballot
__device__ __forceinline__ void waitf(const unsigned* f, unsigned tgt) {
  for (;;) {
    unsigned v = __hip_atomic_load(f, __ATOMIC_RELAXED, __HIP_MEMORY_SCOPE_AGENT);
    if (__ballot(v >= tgt) == ~0ull) return;
    __builtin_amdgcn_s_sleep(1);
  }
}

// ---------------- main persistent GRU kernel ----------------
// 256 blocks x 256 threads. blockIdx = g*64 + jb.
// Block (g,jb): batch rows [g*16,g*16+16), HID cols [jb*16,jb*16+16), full K.
// 4 waves K-split (8 kc each of the h-part); partials reduced via LDS.
__global__ __launch_bounds__(256, 1)
void gru_main(const float* __restrict__ emb,
              const float* __restrict__ bz, const float* __restrict__ br,
              const float* __restrict__ bm, const float* __restrict__ init_h,
              float* __restrict__ out,
              const bf16x8* __restrict__ wh_all, const bf16x8* __restrict__ wl_all,
              unsigned short* __restrict__ hp_hi, unsigned short* __restrict__ hp_lo,
              unsigned short* __restrict__ rp_hi, unsigned short* __restrict__ rp_lo,
              unsigned int* __restrict__ fh, unsigned int* __restrict__ fr)
{
  const int tid  = threadIdx.x;
  const int w    = tid >> 6;
  const int lane = tid & 63;
  const int jb   = blockIdx.x & 63;
  const int g    = blockIdx.x >> 6;
  const int jc   = jb*16 + (lane & 15);   // C/D col
  const int rb   = (lane >> 4) << 2;      // C/D row base within 16-row tile
  const int bb   = g*16 + rb;             // global batch row base

  unsigned int* fh_g = fh + g*1024;       // 64 flags * 16 u32 stride
  unsigned int* fr_g = fr + g*1024;
  const unsigned int* fh_w = fh_g + ((w*16 + (lane & 15)) << 4);  // this wave's 16 producers
  const unsigned int* fr_w = fr_g + ((w*16 + (lane & 15)) << 4);

  const float bzj = bz[jc], brj = br[jc], bmj = bm[jc];
  float st[4];
  #pragma unroll
  for (int r = 0; r < 4; ++r) st[r] = init_h[(size_t)(bb + r)*HID + jc];

  __shared__ f32x4 red1[3][4][64];   // az, ar, amx partials
  __shared__ f32x4 red2[4][64];      // amh partials

  // ---- preload this wave's h-part W slice into registers (48 frags) ----
  const bf16x8* whB = wh_all + ((size_t)jb*48*3)*64 + lane;
  const bf16x8* wlB = wl_all + ((size_t)jb*48*3)*64 + lane;
  bf16x8 Wh[8][3], Wl[8][3];
  #pragma unroll
  for (int i = 0; i < 8; ++i) {
    int kc = 16 + w*8 + i;
    #pragma unroll
    for (int gt = 0; gt < 3; ++gt) {
      Wh[i][gt] = whB[(size_t)(kc*3 + gt)*64];
      Wl[i][gt] = wlB[(size_t)(kc*3 + gt)*64];
    }
  }

  // publish-index constants (owner side)
  const int kc2w   = jc >> 5;
  const int l2base = ((jc & 31) >> 3) << 4;
  const int e7     = jc & 7;

  // A-load base pointers (frag granularity, 2 ull per frag)
  const ull* hbase_hi = (const ull*)hp_hi + ((size_t)g*4096 + (size_t)(w*8)*64 + lane)*2;
  const ull* hbase_lo = (const ull*)hp_lo + ((size_t)g*4096 + (size_t)(w*8)*64 + lane)*2;
  const ull* rbase_hi = (const ull*)rp_hi + ((size_t)g*2048 + (size_t)(w*8)*64 + lane)*2;
  const ull* rbase_lo = (const ull*)rp_lo + ((size_t)g*2048 + (size_t)(w*8)*64 + lane)*2;

  // e-part A source: lane holds emb[t][g*16+(lane&15)][kce*32+(lane>>4)*8 .. +7]
  const float* ebase = emb + (size_t)(g*16 + (lane & 15))*INDIM + ((lane >> 4) << 3);

  for (int t = 0; t < SEQ; ++t) {
    f32x4 az  = {0.f,0.f,0.f,0.f};
    f32x4 ar  = {0.f,0.f,0.f,0.f};
    f32x4 amx = {0.f,0.f,0.f,0.f};
    f32x4 amh = {0.f,0.f,0.f,0.f};

    // ---- e-part (x-projections, K-slice kce = w*4..w*4+3): pre-wait, hides latency ----
    const float* et = ebase + (size_t)t*(BATCH*INDIM);
    #pragma unroll
    for (int q = 0; q < 4; ++q) {
      int kce = w*4 + q;
      const float* s = et + kce*32;
      float4 f0 = ((const float4*)s)[0];
      float4 f1 = ((const float4*)s)[1];
      float v[8] = {f0.x,f0.y,f0.z,f0.w,f1.x,f1.y,f1.z,f1.w};
      bf16x8 eh, el;
      #pragma unroll
      for (int qq = 0; qq < 8; ++qq) {
        unsigned short a, b;
        splitf(v[qq], a, b);
        eh[qq] = (short)a; el[qq] = (short)b;
      }
      bf16x8 wzh = whB[(size_t)(kce*3+0)*64], wzl = wlB[(size_t)(kce*3+0)*64];
      bf16x8 wrh = whB[(size_t)(kce*3+1)*64], wrl = wlB[(size_t)(kce*3+1)*64];
      bf16x8 wmh = whB[(size_t)(kce*3+2)*64], wml = wlB[(size_t)(kce*3+2)*64];
      az  = MFMA16(eh, wzh, az);  az  = MFMA16(eh, wzl, az);  az  = MFMA16(el, wzh, az);
      ar  = MFMA16(eh, wrh, ar);  ar  = MFMA16(eh, wrl, ar);  ar  = MFMA16(el, wrh, ar);
      amx = MFMA16(eh, wmh, amx); amx = MFMA16(eh, wml, amx); amx = MFMA16(el, wmh, amx);
    }

    // ---- wait: this wave's 16 producers have published h(t) ----
    if (t > 0) waitf(fh_w, (unsigned)t);

    // ---- phase 1: z,r h-matmul over this wave's K-slice ----
    const int buf = t & 1;
    const ull* hbh = hbase_hi + (size_t)buf*4096;
    const ull* hbl = hbase_lo + (size_t)buf*4096;
    bf16x8 Ah[8], Al[8];
    loadfrags(Ah, hbh);
    loadfrags(Al, hbl);
    #pragma unroll
    for (int i = 0; i < 8; ++i) {
      az = MFMA16(Ah[i], Wh[i][0], az);
      az = MFMA16(Ah[i], Wl[i][0], az);
      az = MFMA16(Al[i], Wh[i][0], az);
      ar = MFMA16(Ah[i], Wh[i][1], ar);
      ar = MFMA16(Ah[i], Wl[i][1], ar);
      ar = MFMA16(Al[i], Wh[i][1], ar);
    }

    // ---- reduce az, ar (and amx, off the phase-2 critical path) ----
    red1[0][w][lane] = az;
    red1[1][w][lane] = ar;
    red1[2][w][lane] = amx;
    __syncthreads();                                   // S1
    f32x4 azF  = red1[0][0][lane] + red1[0][1][lane] + red1[0][2][lane] + red1[0][3][lane];
    f32x4 arF  = red1[1][0][lane] + red1[1][1][lane] + red1[1][2][lane] + red1[1][3][lane];
    f32x4 amxF = red1[2][0][lane] + red1[2][1][lane] + red1[2][2][lane] + red1[2][3][lane];

    // ---- pointwise 1: z, r, rh = r*h ; publish rh (wave 0 only) ----
    float z[4];
    #pragma unroll
    for (int r = 0; r < 4; ++r) {
      z[r]     = 1.f / (1.f + __expf(-(azF[r] + bzj)));
      float rr = 1.f / (1.f + __expf(-(arF[r] + brj)));
      float rhv = rr * st[r];
      if (w == 0) {
        unsigned short sh, sl;
        splitf(rhv, sh, sl);
        int lane2 = (rb + r) + l2base;
        size_t eidx = ((size_t)kc2w*64 + lane2)*8 + e7;
        __hip_atomic_store(rp_hi + (size_t)g*16384 + eidx, sh,
                           __ATOMIC_RELAXED, __HIP_MEMORY_SCOPE_AGENT);
        __hip_atomic_store(rp_lo + (size_t)g*16384 + eidx, sl,
                           __ATOMIC_RELAXED, __HIP_MEMORY_SCOPE_AGENT);
      }
    }
    if (tid == 0)   // release: drains wave 0's rh stores first
      __hip_atomic_store(fr_g + (jb << 4), (unsigned)(t + 1),
                         __ATOMIC_RELEASE, __HIP_MEMORY_SCOPE_AGENT);

    // ---- wait: this wave's 16 producers have published rh(t) ----
    waitf(fr_w, (unsigned)(t + 1));

    // ---- phase 2: m h-matmul over rh ----
    bf16x8 Bh[8], Bl[8];
    loadfrags(Bh, rbase_hi);
    loadfrags(Bl, rbase_lo);
    #pragma unroll
    for (int i = 0; i < 8; ++i) {
      amh = MFMA16(Bh[i], Wh[i][2], amh);
      amh = MFMA16(Bh[i], Wl[i][2], amh);
      amh = MFMA16(Bl[i], Wh[i][2], amh);
    }

    // ---- reduce amh ----
    red2[w][lane] = amh;
    __syncthreads();                                   // S2
    f32x4 amhF = red2[0][lane] + red2[1][lane] + red2[2][lane] + red2[3][lane];

    // ---- pointwise 2: h_tilde, h_new ; publish h(t+1) (wave 0 only) ----
    const int obuf = buf ^ 1;
    float hnv[4];
    #pragma unroll
    for (int r = 0; r < 4; ++r) {
      float pm = amxF[r] + bmj + amhF[r];
      float e2 = __expf(2.f*pm);
      float ht = 1.f - 2.f/(e2 + 1.f);
      float hn = st[r] + z[r]*(ht - st[r]);
      st[r] = hn; hnv[r] = hn;
      if (w == 0) {
        unsigned short sh, sl;
        splitf(hn, sh, sl);
        int lane2 = (rb + r) + l2base;
        size_t eidx = ((size_t)kc2w*64 + lane2)*8 + e7;
        size_t base = (size_t)g*32768 + (size_t)obuf*16384;
        __hip_atomic_store(hp_hi + base + eidx, sh,
                           __ATOMIC_RELAXED, __HIP_MEMORY_SCOPE_AGENT);
        __hip_atomic_store(hp_lo + base + eidx, sl,
                           __ATOMIC_RELAXED, __HIP_MEMORY_SCOPE_AGENT);
      }
    }
    if (tid == 0)   // release: drains wave 0's h stores first
      __hip_atomic_store(fh_g + (jb << 4), (unsigned)(t + 1),
                         __ATOMIC_RELEASE, __HIP_MEMORY_SCOPE_AGENT);

    // ---- output (off the inter-block critical path) ----
    if (w == 0) {
      #pragma unroll
      for (int r = 0; r < 4; ++r)
        __builtin_nontemporal_store(hnv[r],
            out + (size_t)(bb + r)*(SEQ*HID) + (size_t)t*HID + jc);
    }
  }
}

extern "C" void kernel_launch(void* const* d_in, const int* in_sizes, int n_in,
                              void* d_out, int out_size, void* d_ws, size_t ws_size,
                              hipStream_t stream) {
  const float* emb = (const float*)d_in[0];
  const float* h0  = (const float*)d_in[1];
  const float* Wz  = (const float*)d_in[2];
  const float* bz  = (const float*)d_in[3];
  const float* Wr  = (const float*)d_in[4];
  const float* br  = (const float*)d_in[5];
  const float* Wm  = (const float*)d_in[6];
  const float* bm  = (const float*)d_in[7];
  float* out = (float*)d_out;

  if (ws_size < (size_t)WS_END) return;

  char* ws = (char*)d_ws;
  unsigned int*   fhp  = (unsigned int*)(ws + WS_FH);
  unsigned int*   frp  = (unsigned int*)(ws + WS_FR);
  unsigned short* hphi = (unsigned short*)(ws + WS_HHI);
  unsigned short* hplo = (unsigned short*)(ws + WS_HLO);
  unsigned short* rphi = (unsigned short*)(ws + WS_RHI);
  unsigned short* rplo = (unsigned short*)(ws + WS_RLO);
  bf16x8*         wph  = (bf16x8*)(ws + WS_WHI);
  bf16x8*         wpl  = (bf16x8*)(ws + WS_WLO);

  hipMemsetAsync(ws, 0, 32768, stream);                     // zero both flag arrays
  prep_w<<<2304, 256, 0, stream>>>(Wz, Wr, Wm, wph, wpl);
  prep_h<<<32,   256, 0, stream>>>(h0, (bf16x8*)hphi, (bf16x8*)hplo);
  gru_main<<<256, 256, 0, stream>>>(emb, bz, br, bm, h0, out,
                                    wph, wpl, hphi, hplo, rphi, rplo, fhp, frp);
}